// Round 8
// baseline (486.335 us; speedup 1.0000x reference)
//
#include <hip/hip_runtime.h>

#define N_NODES 50000
#define N_EDGES 800000
#define C_IN    128
#define C_HID   256
#define C_OUT   128
#define SEGB_STRIDE 160   // bf16: [z mean 0..127 | attr 128 | zeros 129..159]
#define EDGE_TILES 12500  // N_EDGES / 64
#define EDGE_GRID  1024

typedef __bf16 bf16x8 __attribute__((ext_vector_type(8)));
typedef float  f32x4  __attribute__((ext_vector_type(4)));

__device__ __forceinline__ unsigned short f2bf(float x) {
    unsigned u = __float_as_uint(x);
    u = (u + 0x7FFF + ((u >> 16) & 1)) >> 16;   // RNE
    return (unsigned short)u;
}

// ---------- fused prep: cast_z | hist | bpack | wa1b | wa2b ----------
__global__ __launch_bounds__(256) void prep_kernel(
    const float* __restrict__ z, const int* __restrict__ ei,
    const float* __restrict__ We1, const float* __restrict__ Wa1,
    const float* __restrict__ Wa2,
    unsigned short* __restrict__ zb, int* __restrict__ cnt,
    unsigned short* __restrict__ Bpack, unsigned short* __restrict__ Wa1b,
    unsigned short* __restrict__ Wa2b)
{
    const int b = blockIdx.x;
    const int tid = threadIdx.x;
    if (b < 6250) {                                   // cast_z: 6250*256 = 1.6M float4
        int t = b * 256 + tid;
        float4 v = ((const float4*)z)[t];
        ushort4 o;
        o.x = f2bf(v.x); o.y = f2bf(v.y); o.z = f2bf(v.z); o.w = f2bf(v.w);
        ((ushort4*)zb)[t] = o;
    } else if (b < 6250 + 3125) {                     // hist: 3125*256 = 800000
        int e = (b - 6250) * 256 + tid;
        atomicAdd(&cnt[ei[N_EDGES + e]], 1);
    } else if (b < 6250 + 3125 + 32) {                // Bpack (edge We1)
        int t = (b - 6250 - 3125) * 256 + tid;        // 8192 lane-slots
        int lane = t & 63, nt = (t >> 6) & 15, ks = t >> 10;
        int n  = nt * 16 + (lane & 15);
        int kb = ks * 32 + (lane >> 4) * 8;
        #pragma unroll
        for (int j = 0; j < 8; ++j)
            Bpack[t * 8 + j] = f2bf(We1[(kb + j) * C_HID + n]);
    } else if (b < 6250 + 3125 + 32 + 20) {           // Wa1b (node layer1)
        int t = (b - 6250 - 3125 - 32) * 256 + tid;
        if (t >= 5 * 16 * 64) return;
        int lane = t & 63, nt = (t >> 6) & 15, ks = t >> 10;
        int n = nt * 16 + (lane & 15);
        #pragma unroll
        for (int j = 0; j < 8; ++j) {
            int k = ks * 32 + (lane >> 4) * 8 + j;
            float v = 0.f;
            if (k < 128)       v = Wa1[(k + 1) * C_HID + n];
            else if (k == 128) v = Wa1[0 * C_HID + n];
            Wa1b[t * 8 + j] = f2bf(v);
        }
    } else {                                          // Wa2b (node layer2)
        int t = (b - 6250 - 3125 - 32 - 20) * 256 + tid;
        if (t >= 8 * 8 * 64) return;
        int lane = t & 63, nt = (t >> 6) & 7, ks = t >> 9;
        int n  = nt * 16 + (lane & 15);
        int kb = ks * 32 + (lane >> 4) * 8;
        #pragma unroll
        for (int j = 0; j < 8; ++j)
            Wa2b[t * 8 + j] = f2bf(Wa2[(kb + j) * C_OUT + n]);
    }
}

// ---------- CSR build ----------

// cnt zero-padded to 50176 ints so int4 reads need no bounds checks.
__global__ __launch_bounds__(256) void scan_kernel(const int* __restrict__ cnt,
                                                   int* __restrict__ offsets) {
    const int tid = threadIdx.x;
    const int per = 196;                        // 49 int4
    const int base = tid * per;
    const int4* c4 = (const int4*)(cnt + base);
    int sum = 0;
    #pragma unroll 7
    for (int i = 0; i < 49; ++i) {
        int4 v = c4[i];
        sum += v.x + v.y + v.z + v.w;
    }
    const int lane = tid & 63, w = tid >> 6;
    int v = sum;
    #pragma unroll
    for (int off = 1; off < 64; off <<= 1) {
        int t = __shfl_up(v, off, 64);
        if (lane >= off) v += t;
    }
    __shared__ int s_w[4];
    if (lane == 63) s_w[w] = v;
    __syncthreads();
    int wbase = 0;
    for (int i = 0; i < w; ++i) wbase += s_w[i];
    int run = wbase + v - sum;
    for (int i = 0; i < per; ++i) {
        int b = base + i;
        if (b < N_NODES) { offsets[b] = run; run += cnt[b]; }
    }
    if (tid == 255) offsets[N_NODES] = run;
}

__global__ void fill_kernel(const int* __restrict__ ei, const float* __restrict__ eattr,
                            const int* __restrict__ offsets, int* __restrict__ cursor,
                            int* __restrict__ esrc, int* __restrict__ edst,
                            int* __restrict__ perm, float* __restrict__ eatt) {
    int e = blockIdx.x * 256 + threadIdx.x;
    if (e >= N_EDGES) return;
    int d = ei[N_EDGES + e];
    int pos = atomicAdd(&cursor[d], 1);
    int slot = offsets[d] + pos;
    esrc[slot] = ei[e];
    edst[slot] = d;
    perm[slot] = e;
    eatt[slot] = eattr[e];
}

// ---------- gather-mean (bf16 in, bf16 out, fused normalize, 4x ILP) ----------
__global__ __launch_bounds__(256) void gather_kernel(
    const unsigned short* __restrict__ zb, const int* __restrict__ offsets,
    const int* __restrict__ esrc, const float* __restrict__ eatt,
    unsigned short* __restrict__ segb)
{
    const int w = threadIdx.x >> 6, lane = threadIdx.x & 63;
    const int n = blockIdx.x * 4 + w;
    if (n >= N_NODES) return;
    const int beg = offsets[n], end = offsets[n + 1], deg = end - beg;

    float ax = 0.f, ay = 0.f;                  // lane owns channels lane*2, lane*2+1
    int i = beg;
    for (; i + 4 <= end; i += 4) {
        int s0 = esrc[i], s1 = esrc[i + 1], s2 = esrc[i + 2], s3 = esrc[i + 3];
        unsigned u0 = *(const unsigned*)(zb + (size_t)s0 * C_IN + lane * 2);
        unsigned u1 = *(const unsigned*)(zb + (size_t)s1 * C_IN + lane * 2);
        unsigned u2 = *(const unsigned*)(zb + (size_t)s2 * C_IN + lane * 2);
        unsigned u3 = *(const unsigned*)(zb + (size_t)s3 * C_IN + lane * 2);
        ax += __uint_as_float(u0 << 16) + __uint_as_float(u1 << 16)
            + __uint_as_float(u2 << 16) + __uint_as_float(u3 << 16);
        ay += __uint_as_float(u0 & 0xffff0000u) + __uint_as_float(u1 & 0xffff0000u)
            + __uint_as_float(u2 & 0xffff0000u) + __uint_as_float(u3 & 0xffff0000u);
    }
    for (; i < end; ++i) {
        int s = esrc[i];
        unsigned u = *(const unsigned*)(zb + (size_t)s * C_IN + lane * 2);
        ax += __uint_as_float(u << 16);
        ay += __uint_as_float(u & 0xffff0000u);
    }
    float asum = 0.f;
    for (int j = beg + lane; j < end; j += 64) asum += eatt[j];
    #pragma unroll
    for (int off = 1; off < 64; off <<= 1) asum += __shfl_xor(asum, off, 64);

    const float inv = (deg > 0) ? 1.0f / (float)deg : 0.0f;
    unsigned short* segn = segb + (size_t)n * SEGB_STRIDE;
    ushort2 o; o.x = f2bf(ax * inv); o.y = f2bf(ay * inv);
    *(ushort2*)(segn + lane * 2) = o;
    if (lane < 16) {
        ushort2 p; p.x = (lane == 0) ? f2bf(asum * inv) : 0; p.y = 0;
        *(ushort2*)(segn + 128 + lane * 2) = p;   // attr @128, zeros 129..159
    }
}

// ---------- edge MLP: persistent, software-pipelined bf16 MFMA ----------
// 1024 blocks, each owns a contiguous CSR tile range. B-frags loaded once per
// block; next tile's A gathered into regs during current tile's MFMA phase;
// cross-wave s_red double-buffered so the drain folds into the top barrier.
__global__ __launch_bounds__(512) void edge_mfma_kernel(
    const unsigned short* __restrict__ zb, const int* __restrict__ esrc,
    const int* __restrict__ edst, const int* __restrict__ perm,
    const unsigned short* __restrict__ Bpack,
    const float* __restrict__ be1, const float* __restrict__ We2,
    const float* __restrict__ be2, float* __restrict__ edge_out)
{
    __shared__ __align__(16) unsigned short s_a[64][264];
    __shared__ float s_red[2][8][64];
    const int tid  = threadIdx.x;
    const int lane = tid & 63, w = tid >> 6;      // w 0..7
    const int m16 = lane & 15, quad = lane >> 4;
    const int l16 = tid & 15;
    const int hrq = tid >> 4;                     // 0..31

    const int t_beg = (int)(((long long)blockIdx.x * EDGE_TILES) / EDGE_GRID);
    const int t_end = (int)(((long long)(blockIdx.x + 1) * EDGE_TILES) / EDGE_GRID);

    // B frags + epilogue constants: once per block
    bf16x8 bfr[8][2];
    {
        const bf16x8* bp = (const bf16x8*)Bpack;
        #pragma unroll
        for (int ks = 0; ks < 8; ++ks)
            #pragma unroll
            for (int nt = 0; nt < 2; ++nt)
                bfr[ks][nt] = bp[(ks * 16 + (w * 2 + nt)) * 64 + lane];
    }
    const float be2v = be2[0];
    float b1v[2], w2v[2];
    #pragma unroll
    for (int nt = 0; nt < 2; ++nt) {
        int n = w * 32 + nt * 16 + m16;
        b1v[nt] = be1[n]; w2v[nt] = We2[n];
    }

    // prefetch tile t_beg into regs
    bf16x8 v[4];
    #pragma unroll
    for (int it = 0; it < 4; ++it) {
        int hr = it * 32 + hrq;
        int slot = t_beg * 64 + (hr >> 1);
        int node = (hr & 1) ? edst[slot] : esrc[slot];
        v[it] = *(const bf16x8*)(zb + (size_t)node * C_IN + l16 * 8);
    }

    int buf = 0;
    for (int t = t_beg; t < t_end; ++t) {
        __syncthreads();   // prev MFMA done reading s_a; s_red[buf^1] stable
        // commit staged A (consumes v)
        #pragma unroll
        for (int it = 0; it < 4; ++it) {
            int hr = it * 32 + hrq;
            *(bf16x8*)&s_a[hr >> 1][(hr & 1) * 128 + l16 * 8] = v[it];
        }
        // drain previous tile's result
        if (t > t_beg && tid < 64) {
            float r = be2v;
            #pragma unroll
            for (int ww = 0; ww < 8; ++ww) r += s_red[buf ^ 1][ww][tid];
            edge_out[perm[(t - 1) * 64 + tid]] = r;
        }
        // prefetch next tile (in flight through the MFMA phase)
        if (t + 1 < t_end) {
            #pragma unroll
            for (int it = 0; it < 4; ++it) {
                int hr = it * 32 + hrq;
                int slot = (t + 1) * 64 + (hr >> 1);
                int node = (hr & 1) ? edst[slot] : esrc[slot];
                v[it] = *(const bf16x8*)(zb + (size_t)node * C_IN + l16 * 8);
            }
        }
        __syncthreads();   // s_a visible

        f32x4 acc[4][2];
        #pragma unroll
        for (int mt = 0; mt < 4; ++mt)
            #pragma unroll
            for (int nt = 0; nt < 2; ++nt)
                acc[mt][nt] = (f32x4){0.f, 0.f, 0.f, 0.f};

        #pragma unroll
        for (int ks = 0; ks < 8; ++ks) {
            #pragma unroll
            for (int mt = 0; mt < 4; ++mt) {
                bf16x8 a = *(const bf16x8*)&s_a[mt * 16 + m16][ks * 32 + quad * 8];
                #pragma unroll
                for (int nt = 0; nt < 2; ++nt)
                    acc[mt][nt] = __builtin_amdgcn_mfma_f32_16x16x32_bf16(
                        a, bfr[ks][nt], acc[mt][nt], 0, 0, 0);
            }
        }

        // epilogue: relu(acc + be1) dot We2 over this wave's 32 cols
        float esum[4][4];
        #pragma unroll
        for (int mt = 0; mt < 4; ++mt)
            #pragma unroll
            for (int r = 0; r < 4; ++r) esum[mt][r] = 0.f;
        #pragma unroll
        for (int nt = 0; nt < 2; ++nt) {
            #pragma unroll
            for (int mt = 0; mt < 4; ++mt)
                #pragma unroll
                for (int r = 0; r < 4; ++r) {
                    float h = fmaxf(acc[mt][nt][r] + b1v[nt], 0.f);
                    esum[mt][r] += h * w2v[nt];
                }
        }
        #pragma unroll
        for (int off = 1; off <= 8; off <<= 1)
            #pragma unroll
            for (int mt = 0; mt < 4; ++mt)
                #pragma unroll
                for (int r = 0; r < 4; ++r)
                    esum[mt][r] += __shfl_xor(esum[mt][r], off, 64);
        if (m16 == 0) {
            #pragma unroll
            for (int mt = 0; mt < 4; ++mt)
                #pragma unroll
                for (int r = 0; r < 4; ++r)
                    s_red[buf][w][mt * 16 + quad * 4 + r] = esum[mt][r];
        }
        buf ^= 1;
    }
    __syncthreads();
    if (tid < 64) {
        float r = be2v;
        #pragma unroll
        for (int ww = 0; ww < 8; ++ww) r += s_red[buf ^ 1][ww][tid];
        edge_out[perm[(t_end - 1) * 64 + tid]] = r;
    }
}

// ---------- node MLP: bf16 MFMA, both layers, h via LDS round-trip ----------
__global__ __launch_bounds__(256, 2) void node_mfma_kernel(
    const unsigned short* __restrict__ segb, const unsigned short* __restrict__ Wa1b,
    const float* __restrict__ ba1, const unsigned short* __restrict__ Wa2b,
    const float* __restrict__ ba2, float* __restrict__ x_out)
{
    __shared__ __align__(16) unsigned short s_a[64][168];
    __shared__ __align__(16) unsigned short s_h[64][264];
    const int tid  = threadIdx.x;
    const int lane = tid & 63, w = tid >> 6;
    const int m16 = lane & 15, quad = lane >> 4;
    const int n0 = blockIdx.x * 64;

    {
        const unsigned short* src = segb + (size_t)n0 * SEGB_STRIDE;
        #pragma unroll
        for (int i = 0; i < 5; ++i) {
            int c = tid + i * 256;
            int row = c / 20, col = c - row * 20;
            *(uint4*)&s_a[row][col * 8] = *(const uint4*)(src + c * 8);
        }
    }

    bf16x8 bfr1[5][4];
    {
        const bf16x8* bp = (const bf16x8*)Wa1b;
        #pragma unroll
        for (int ks = 0; ks < 5; ++ks)
            #pragma unroll
            for (int nt = 0; nt < 4; ++nt)
                bfr1[ks][nt] = bp[(ks * 16 + (w * 4 + nt)) * 64 + lane];
    }
    __syncthreads();

    f32x4 acc1[4][4];
    #pragma unroll
    for (int mt = 0; mt < 4; ++mt)
        #pragma unroll
        for (int nt = 0; nt < 4; ++nt)
            acc1[mt][nt] = (f32x4){0.f, 0.f, 0.f, 0.f};

    #pragma unroll
    for (int ks = 0; ks < 5; ++ks) {
        #pragma unroll
        for (int mt = 0; mt < 4; ++mt) {
            bf16x8 a = *(const bf16x8*)&s_a[mt * 16 + m16][ks * 32 + quad * 8];
            #pragma unroll
            for (int nt = 0; nt < 4; ++nt)
                acc1[mt][nt] = __builtin_amdgcn_mfma_f32_16x16x32_bf16(
                    a, bfr1[ks][nt], acc1[mt][nt], 0, 0, 0);
        }
    }

    #pragma unroll
    for (int nt = 0; nt < 4; ++nt) {
        const int chan = w * 64 + nt * 16 + m16;
        const float b1 = ba1[chan];
        #pragma unroll
        for (int mt = 0; mt < 4; ++mt)
            #pragma unroll
            for (int r = 0; r < 4; ++r) {
                const int node = mt * 16 + quad * 4 + r;
                s_h[node][chan] = f2bf(fmaxf(acc1[mt][nt][r] + b1, 0.f));
            }
    }

    bf16x8 bfr2[8][2];
    {
        const bf16x8* bp = (const bf16x8*)Wa2b;
        #pragma unroll
        for (int ks = 0; ks < 8; ++ks)
            #pragma unroll
            for (int nt = 0; nt < 2; ++nt)
                bfr2[ks][nt] = bp[(ks * 8 + (w * 2 + nt)) * 64 + lane];
    }
    __syncthreads();

    f32x4 acc2[4][2];
    #pragma unroll
    for (int mt = 0; mt < 4; ++mt)
        #pragma unroll
        for (int nt = 0; nt < 2; ++nt)
            acc2[mt][nt] = (f32x4){0.f, 0.f, 0.f, 0.f};

    #pragma unroll
    for (int ks = 0; ks < 8; ++ks) {
        #pragma unroll
        for (int mt = 0; mt < 4; ++mt) {
            bf16x8 a = *(const bf16x8*)&s_h[mt * 16 + m16][ks * 32 + quad * 8];
            #pragma unroll
            for (int nt = 0; nt < 2; ++nt)
                acc2[mt][nt] = __builtin_amdgcn_mfma_f32_16x16x32_bf16(
                    a, bfr2[ks][nt], acc2[mt][nt], 0, 0, 0);
        }
    }

    #pragma unroll
    for (int nt = 0; nt < 2; ++nt) {
        const int j = w * 32 + nt * 16 + m16;
        const float b2 = ba2[j];
        #pragma unroll
        for (int mt = 0; mt < 4; ++mt)
            #pragma unroll
            for (int r = 0; r < 4; ++r) {
                const int node = n0 + mt * 16 + quad * 4 + r;
                if (node < N_NODES)
                    x_out[(size_t)node * C_OUT + j] = acc2[mt][nt][r] + b2;
            }
    }
}

// ---------- launch ----------
// ws layout (bytes):
//   segb    16,015,360   (50048 rows x 160 bf16)
//   zb      12,800,000
//   Bpack      131,072
//   Wa1b        81,920
//   Wa2b        65,536
//   cnt        200,704   (50176 ints, zero-padded for int4 scan)
//   cursor     200,704
//   offsets    200,064
//   esrc     3,200,000
//   edst     3,200,000
//   perm     3,200,000
//   eatt     3,200,000    => ~42.5 MB

extern "C" void kernel_launch(void* const* d_in, const int* in_sizes, int n_in,
                              void* d_out, int out_size, void* d_ws, size_t ws_size,
                              hipStream_t stream) {
    const float* z     = (const float*)d_in[0];
    const int*   ei    = (const int*)d_in[1];     // int32 per harness contract
    const float* eattr = (const float*)d_in[2];
    const float* Wa1   = (const float*)d_in[3];
    const float* ba1   = (const float*)d_in[4];
    const float* Wa2   = (const float*)d_in[5];
    const float* ba2   = (const float*)d_in[6];
    const float* We1   = (const float*)d_in[7];
    const float* be1   = (const float*)d_in[8];
    const float* We2   = (const float*)d_in[9];
    const float* be2   = (const float*)d_in[10];

    float* x_out    = (float*)d_out;
    float* edge_out = x_out + (size_t)N_NODES * C_OUT;

    char* wsb = (char*)d_ws;
    size_t off = 0;
    unsigned short* segb    = (unsigned short*)(wsb + off); off += 16015360;
    unsigned short* zb      = (unsigned short*)(wsb + off); off += 12800000;
    unsigned short* Bpack   = (unsigned short*)(wsb + off); off += 131072;
    unsigned short* Wa1b    = (unsigned short*)(wsb + off); off += 81920;
    unsigned short* Wa2b    = (unsigned short*)(wsb + off); off += 65536;
    int*            cnt     = (int*)(wsb + off);            off += 200704;
    int*            cursor  = (int*)(wsb + off);            off += 200704;
    int*            offsets = (int*)(wsb + off);            off += 200064;
    int*            esrc    = (int*)(wsb + off);            off += 3200000;
    int*            edst    = (int*)(wsb + off);            off += 3200000;
    int*            perm    = (int*)(wsb + off);            off += 3200000;
    float*          eatt    = (float*)(wsb + off);          off += 3200000;

    hipMemsetAsync(cnt, 0, 2 * 200704, stream);   // cnt + cursor (adjacent)

    prep_kernel<<<6250 + 3125 + 32 + 20 + 16, 256, 0, stream>>>(
        z, ei, We1, Wa1, Wa2, zb, cnt, Bpack, Wa1b, Wa2b);

    scan_kernel<<<1, 256, 0, stream>>>(cnt, offsets);
    fill_kernel<<<(N_EDGES + 255) / 256, 256, 0, stream>>>(ei, eattr, offsets, cursor,
                                                           esrc, edst, perm, eatt);

    edge_mfma_kernel<<<EDGE_GRID, 512, 0, stream>>>(zb, esrc, edst, perm, Bpack,
                                                    be1, We2, be2, edge_out);

    gather_kernel<<<(N_NODES + 3) / 4, 256, 0, stream>>>(zb, offsets, esrc, eatt, segb);
    node_mfma_kernel<<<(N_NODES + 63) / 64, 256, 0, stream>>>(segb, Wa1b, ba1, Wa2b,
                                                              ba2, x_out);
}

// Round 9
// 461.720 us; speedup vs baseline: 1.0533x; 1.0533x over previous
//
#include <hip/hip_runtime.h>

#define N_NODES 50000
#define N_EDGES 800000
#define C_IN    128
#define C_HID   256
#define C_OUT   128
#define SEGB_STRIDE 160   // bf16: [z mean 0..127 | attr 128 | zeros 129..159]
#define EDGE_TILES 25000  // N_EDGES / 32
#define EDGE_GRID  1024

typedef __bf16 bf16x8 __attribute__((ext_vector_type(8)));
typedef float  f32x4  __attribute__((ext_vector_type(4)));

__device__ __forceinline__ unsigned short f2bf(float x) {
    unsigned u = __float_as_uint(x);
    u = (u + 0x7FFF + ((u >> 16) & 1)) >> 16;   // RNE
    return (unsigned short)u;
}

// ---------- fused prep: cast_z | hist | bpack | wa1b | wa2b ----------
__global__ __launch_bounds__(256) void prep_kernel(
    const float* __restrict__ z, const int* __restrict__ ei,
    const float* __restrict__ We1, const float* __restrict__ Wa1,
    const float* __restrict__ Wa2,
    unsigned short* __restrict__ zb, int* __restrict__ cnt,
    unsigned short* __restrict__ Bpack, unsigned short* __restrict__ Wa1b,
    unsigned short* __restrict__ Wa2b)
{
    const int b = blockIdx.x;
    const int tid = threadIdx.x;
    if (b < 6250) {                                   // cast_z: 6250*256 = 1.6M float4
        int t = b * 256 + tid;
        float4 v = ((const float4*)z)[t];
        ushort4 o;
        o.x = f2bf(v.x); o.y = f2bf(v.y); o.z = f2bf(v.z); o.w = f2bf(v.w);
        ((ushort4*)zb)[t] = o;
    } else if (b < 6250 + 3125) {                     // hist: 3125*256 = 800000
        int e = (b - 6250) * 256 + tid;
        atomicAdd(&cnt[ei[N_EDGES + e]], 1);
    } else if (b < 6250 + 3125 + 32) {                // Bpack (edge We1)
        int t = (b - 6250 - 3125) * 256 + tid;        // 8192 lane-slots
        int lane = t & 63, nt = (t >> 6) & 15, ks = t >> 10;
        int n  = nt * 16 + (lane & 15);
        int kb = ks * 32 + (lane >> 4) * 8;
        #pragma unroll
        for (int j = 0; j < 8; ++j)
            Bpack[t * 8 + j] = f2bf(We1[(kb + j) * C_HID + n]);
    } else if (b < 6250 + 3125 + 32 + 20) {           // Wa1b (node layer1)
        int t = (b - 6250 - 3125 - 32) * 256 + tid;
        if (t >= 5 * 16 * 64) return;
        int lane = t & 63, nt = (t >> 6) & 15, ks = t >> 10;
        int n = nt * 16 + (lane & 15);
        #pragma unroll
        for (int j = 0; j < 8; ++j) {
            int k = ks * 32 + (lane >> 4) * 8 + j;
            float v = 0.f;
            if (k < 128)       v = Wa1[(k + 1) * C_HID + n];
            else if (k == 128) v = Wa1[0 * C_HID + n];
            Wa1b[t * 8 + j] = f2bf(v);
        }
    } else {                                          // Wa2b (node layer2)
        int t = (b - 6250 - 3125 - 32 - 20) * 256 + tid;
        if (t >= 8 * 8 * 64) return;
        int lane = t & 63, nt = (t >> 6) & 7, ks = t >> 9;
        int n  = nt * 16 + (lane & 15);
        int kb = ks * 32 + (lane >> 4) * 8;
        #pragma unroll
        for (int j = 0; j < 8; ++j)
            Wa2b[t * 8 + j] = f2bf(Wa2[(kb + j) * C_OUT + n]);
    }
}

// ---------- CSR build ----------

// cnt zero-padded to 50176 ints so int4 reads need no bounds checks.
__global__ __launch_bounds__(256) void scan_kernel(const int* __restrict__ cnt,
                                                   int* __restrict__ offsets) {
    const int tid = threadIdx.x;
    const int per = 196;                        // 49 int4
    const int base = tid * per;
    const int4* c4 = (const int4*)(cnt + base);
    int sum = 0;
    #pragma unroll 7
    for (int i = 0; i < 49; ++i) {
        int4 v = c4[i];
        sum += v.x + v.y + v.z + v.w;
    }
    const int lane = tid & 63, w = tid >> 6;
    int v = sum;
    #pragma unroll
    for (int off = 1; off < 64; off <<= 1) {
        int t = __shfl_up(v, off, 64);
        if (lane >= off) v += t;
    }
    __shared__ int s_w[4];
    if (lane == 63) s_w[w] = v;
    __syncthreads();
    int wbase = 0;
    for (int i = 0; i < w; ++i) wbase += s_w[i];
    int run = wbase + v - sum;
    for (int i = 0; i < per; ++i) {
        int b = base + i;
        if (b < N_NODES) { offsets[b] = run; run += cnt[b]; }
    }
    if (tid == 255) offsets[N_NODES] = run;
}

__global__ void fill_kernel(const int* __restrict__ ei, const float* __restrict__ eattr,
                            const int* __restrict__ offsets, int* __restrict__ cursor,
                            int* __restrict__ esrc, int* __restrict__ edst,
                            int* __restrict__ perm, float* __restrict__ eatt) {
    int e = blockIdx.x * 256 + threadIdx.x;
    if (e >= N_EDGES) return;
    int d = ei[N_EDGES + e];
    int pos = atomicAdd(&cursor[d], 1);
    int slot = offsets[d] + pos;
    esrc[slot] = ei[e];
    edst[slot] = d;
    perm[slot] = e;
    eatt[slot] = eattr[e];
}

// ---------- gather-mean (bf16 in, bf16 out, fused normalize, 4x ILP) ----------
__global__ __launch_bounds__(256) void gather_kernel(
    const unsigned short* __restrict__ zb, const int* __restrict__ offsets,
    const int* __restrict__ esrc, const float* __restrict__ eatt,
    unsigned short* __restrict__ segb)
{
    const int w = threadIdx.x >> 6, lane = threadIdx.x & 63;
    const int n = blockIdx.x * 4 + w;
    if (n >= N_NODES) return;
    const int beg = offsets[n], end = offsets[n + 1], deg = end - beg;

    float ax = 0.f, ay = 0.f;                  // lane owns channels lane*2, lane*2+1
    int i = beg;
    for (; i + 4 <= end; i += 4) {
        int s0 = esrc[i], s1 = esrc[i + 1], s2 = esrc[i + 2], s3 = esrc[i + 3];
        unsigned u0 = *(const unsigned*)(zb + (size_t)s0 * C_IN + lane * 2);
        unsigned u1 = *(const unsigned*)(zb + (size_t)s1 * C_IN + lane * 2);
        unsigned u2 = *(const unsigned*)(zb + (size_t)s2 * C_IN + lane * 2);
        unsigned u3 = *(const unsigned*)(zb + (size_t)s3 * C_IN + lane * 2);
        ax += __uint_as_float(u0 << 16) + __uint_as_float(u1 << 16)
            + __uint_as_float(u2 << 16) + __uint_as_float(u3 << 16);
        ay += __uint_as_float(u0 & 0xffff0000u) + __uint_as_float(u1 & 0xffff0000u)
            + __uint_as_float(u2 & 0xffff0000u) + __uint_as_float(u3 & 0xffff0000u);
    }
    for (; i < end; ++i) {
        int s = esrc[i];
        unsigned u = *(const unsigned*)(zb + (size_t)s * C_IN + lane * 2);
        ax += __uint_as_float(u << 16);
        ay += __uint_as_float(u & 0xffff0000u);
    }
    float asum = 0.f;
    for (int j = beg + lane; j < end; j += 64) asum += eatt[j];
    #pragma unroll
    for (int off = 1; off < 64; off <<= 1) asum += __shfl_xor(asum, off, 64);

    const float inv = (deg > 0) ? 1.0f / (float)deg : 0.0f;
    unsigned short* segn = segb + (size_t)n * SEGB_STRIDE;
    ushort2 o; o.x = f2bf(ax * inv); o.y = f2bf(ay * inv);
    *(ushort2*)(segn + lane * 2) = o;
    if (lane < 16) {
        ushort2 p; p.x = (lane == 0) ? f2bf(asum * inv) : 0; p.y = 0;
        *(ushort2*)(segn + 128 + lane * 2) = p;   // attr @128, zeros 129..159
    }
}

// ---------- edge MLP: persistent bf16 MFMA, TRUE double-buffered LDS ----------
// One barrier per 32-edge tile. Loads for tile t+1 are issued AFTER the barrier
// and committed to LDS AFTER the MFMA phase, so the compiler's vmcnt(0)-before-
// s_barrier drain is free and the gather latency rides under the MFMA.
// M=32 tiles keep the double buffer at 35.8 KB LDS -> 4 blocks/CU.
__global__ __launch_bounds__(512) void edge_mfma_kernel(
    const unsigned short* __restrict__ zb, const int* __restrict__ esrc,
    const int* __restrict__ edst, const int* __restrict__ perm,
    const unsigned short* __restrict__ Bpack,
    const float* __restrict__ be1, const float* __restrict__ We2,
    const float* __restrict__ be2, float* __restrict__ edge_out)
{
    __shared__ __align__(16) unsigned short s_a[2][32][264];
    __shared__ float s_red[2][8][32];
    const int tid  = threadIdx.x;
    const int lane = tid & 63, w = tid >> 6;      // w 0..7
    const int m16 = lane & 15, quad = lane >> 4;

    const int t_beg = (int)(((long long)blockIdx.x * EDGE_TILES) / EDGE_GRID);
    const int t_end = (int)(((long long)(blockIdx.x + 1) * EDGE_TILES) / EDGE_GRID);

    // B frags + epilogue constants: once per block (wave w owns cols [w*32, w*32+32))
    bf16x8 bfr[8][2];
    {
        const bf16x8* bp = (const bf16x8*)Bpack;
        #pragma unroll
        for (int ks = 0; ks < 8; ++ks)
            #pragma unroll
            for (int nt = 0; nt < 2; ++nt)
                bfr[ks][nt] = bp[(ks * 16 + (w * 2 + nt)) * 64 + lane];
    }
    const float be2v = be2[0];
    float b1v[2], w2v[2];
    #pragma unroll
    for (int nt = 0; nt < 2; ++nt) {
        int n = w * 32 + nt * 16 + m16;
        b1v[nt] = be1[n]; w2v[nt] = We2[n];
    }

    // staging map: 64 half-rows x 16 chunks(16B) = 1024 chunks; 2 per thread
    bf16x8 v[2];
    const int c0 = tid, c1 = tid + 512;
    const int row0 = c0 >> 4, row1 = c1 >> 4;
    const int col0 = (c0 & 15) * 8, col1 = (c1 & 15) * 8;

    // prologue: tile t_beg -> s_a[0]
    {
        int slot0 = t_beg * 32 + (row0 >> 1);
        int slot1 = t_beg * 32 + (row1 >> 1);
        int n0 = (row0 & 1) ? edst[slot0] : esrc[slot0];
        int n1 = (row1 & 1) ? edst[slot1] : esrc[slot1];
        v[0] = *(const bf16x8*)(zb + (size_t)n0 * C_IN + col0);
        v[1] = *(const bf16x8*)(zb + (size_t)n1 * C_IN + col1);
        *(bf16x8*)&s_a[0][row0 >> 1][(row0 & 1) * 128 + col0] = v[0];
        *(bf16x8*)&s_a[0][row1 >> 1][(row1 & 1) * 128 + col1] = v[1];
    }

    int buf = 0;
    for (int t = t_beg; t < t_end; ++t) {
        __syncthreads();   // s_a[buf] committed; s_red[buf^1] stable; nothing in flight

        // drain tile t-1
        if (t > t_beg && tid < 32) {
            float r = be2v;
            #pragma unroll
            for (int ww = 0; ww < 8; ++ww) r += s_red[buf ^ 1][ww][tid];
            edge_out[perm[(t - 1) * 32 + tid]] = r;
        }

        // issue gather loads for t+1 (ride under the MFMA phase)
        if (t + 1 < t_end) {
            int slot0 = (t + 1) * 32 + (row0 >> 1);
            int slot1 = (t + 1) * 32 + (row1 >> 1);
            int n0 = (row0 & 1) ? edst[slot0] : esrc[slot0];
            int n1 = (row1 & 1) ? edst[slot1] : esrc[slot1];
            v[0] = *(const bf16x8*)(zb + (size_t)n0 * C_IN + col0);
            v[1] = *(const bf16x8*)(zb + (size_t)n1 * C_IN + col1);
        }

        // MFMA on s_a[buf]: M32 x K256 x N32 per wave
        f32x4 acc[2][2];
        #pragma unroll
        for (int mt = 0; mt < 2; ++mt)
            #pragma unroll
            for (int nt = 0; nt < 2; ++nt)
                acc[mt][nt] = (f32x4){0.f, 0.f, 0.f, 0.f};

        #pragma unroll
        for (int ks = 0; ks < 8; ++ks) {
            #pragma unroll
            for (int mt = 0; mt < 2; ++mt) {
                bf16x8 a = *(const bf16x8*)&s_a[buf][mt * 16 + m16][ks * 32 + quad * 8];
                #pragma unroll
                for (int nt = 0; nt < 2; ++nt)
                    acc[mt][nt] = __builtin_amdgcn_mfma_f32_16x16x32_bf16(
                        a, bfr[ks][nt], acc[mt][nt], 0, 0, 0);
            }
        }

        // epilogue: relu(acc + be1) dot We2 over this wave's 32 cols
        float esum[2][4];
        #pragma unroll
        for (int mt = 0; mt < 2; ++mt)
            #pragma unroll
            for (int r = 0; r < 4; ++r) esum[mt][r] = 0.f;
        #pragma unroll
        for (int nt = 0; nt < 2; ++nt) {
            #pragma unroll
            for (int mt = 0; mt < 2; ++mt)
                #pragma unroll
                for (int r = 0; r < 4; ++r) {
                    float h = fmaxf(acc[mt][nt][r] + b1v[nt], 0.f);
                    esum[mt][r] += h * w2v[nt];
                }
        }
        #pragma unroll
        for (int off = 1; off <= 8; off <<= 1)
            #pragma unroll
            for (int mt = 0; mt < 2; ++mt)
                #pragma unroll
                for (int r = 0; r < 4; ++r)
                    esum[mt][r] += __shfl_xor(esum[mt][r], off, 64);
        if (m16 == 0) {
            #pragma unroll
            for (int mt = 0; mt < 2; ++mt)
                #pragma unroll
                for (int r = 0; r < 4; ++r)
                    s_red[buf][w][mt * 16 + quad * 4 + r] = esum[mt][r];
        }

        // commit t+1 staging (vmcnt wait lands here, after MFMA issued)
        if (t + 1 < t_end) {
            *(bf16x8*)&s_a[buf ^ 1][row0 >> 1][(row0 & 1) * 128 + col0] = v[0];
            *(bf16x8*)&s_a[buf ^ 1][row1 >> 1][(row1 & 1) * 128 + col1] = v[1];
        }
        buf ^= 1;
    }
    __syncthreads();
    if (tid < 32) {
        float r = be2v;
        #pragma unroll
        for (int ww = 0; ww < 8; ++ww) r += s_red[buf ^ 1][ww][tid];
        edge_out[perm[(t_end - 1) * 32 + tid]] = r;
    }
}

// ---------- node MLP: bf16 MFMA, both layers, h via LDS round-trip ----------
__global__ __launch_bounds__(256, 2) void node_mfma_kernel(
    const unsigned short* __restrict__ segb, const unsigned short* __restrict__ Wa1b,
    const float* __restrict__ ba1, const unsigned short* __restrict__ Wa2b,
    const float* __restrict__ ba2, float* __restrict__ x_out)
{
    __shared__ __align__(16) unsigned short s_a[64][168];
    __shared__ __align__(16) unsigned short s_h[64][264];
    const int tid  = threadIdx.x;
    const int lane = tid & 63, w = tid >> 6;
    const int m16 = lane & 15, quad = lane >> 4;
    const int n0 = blockIdx.x * 64;

    {
        const unsigned short* src = segb + (size_t)n0 * SEGB_STRIDE;
        #pragma unroll
        for (int i = 0; i < 5; ++i) {
            int c = tid + i * 256;
            int row = c / 20, col = c - row * 20;
            *(uint4*)&s_a[row][col * 8] = *(const uint4*)(src + c * 8);
        }
    }

    bf16x8 bfr1[5][4];
    {
        const bf16x8* bp = (const bf16x8*)Wa1b;
        #pragma unroll
        for (int ks = 0; ks < 5; ++ks)
            #pragma unroll
            for (int nt = 0; nt < 4; ++nt)
                bfr1[ks][nt] = bp[(ks * 16 + (w * 4 + nt)) * 64 + lane];
    }
    __syncthreads();

    f32x4 acc1[4][4];
    #pragma unroll
    for (int mt = 0; mt < 4; ++mt)
        #pragma unroll
        for (int nt = 0; nt < 4; ++nt)
            acc1[mt][nt] = (f32x4){0.f, 0.f, 0.f, 0.f};

    #pragma unroll
    for (int ks = 0; ks < 5; ++ks) {
        #pragma unroll
        for (int mt = 0; mt < 4; ++mt) {
            bf16x8 a = *(const bf16x8*)&s_a[mt * 16 + m16][ks * 32 + quad * 8];
            #pragma unroll
            for (int nt = 0; nt < 4; ++nt)
                acc1[mt][nt] = __builtin_amdgcn_mfma_f32_16x16x32_bf16(
                    a, bfr1[ks][nt], acc1[mt][nt], 0, 0, 0);
        }
    }

    #pragma unroll
    for (int nt = 0; nt < 4; ++nt) {
        const int chan = w * 64 + nt * 16 + m16;
        const float b1 = ba1[chan];
        #pragma unroll
        for (int mt = 0; mt < 4; ++mt)
            #pragma unroll
            for (int r = 0; r < 4; ++r) {
                const int node = mt * 16 + quad * 4 + r;
                s_h[node][chan] = f2bf(fmaxf(acc1[mt][nt][r] + b1, 0.f));
            }
    }

    bf16x8 bfr2[8][2];
    {
        const bf16x8* bp = (const bf16x8*)Wa2b;
        #pragma unroll
        for (int ks = 0; ks < 8; ++ks)
            #pragma unroll
            for (int nt = 0; nt < 2; ++nt)
                bfr2[ks][nt] = bp[(ks * 8 + (w * 2 + nt)) * 64 + lane];
    }
    __syncthreads();

    f32x4 acc2[4][2];
    #pragma unroll
    for (int mt = 0; mt < 4; ++mt)
        #pragma unroll
        for (int nt = 0; nt < 2; ++nt)
            acc2[mt][nt] = (f32x4){0.f, 0.f, 0.f, 0.f};

    #pragma unroll
    for (int ks = 0; ks < 8; ++ks) {
        #pragma unroll
        for (int mt = 0; mt < 4; ++mt) {
            bf16x8 a = *(const bf16x8*)&s_h[mt * 16 + m16][ks * 32 + quad * 8];
            #pragma unroll
            for (int nt = 0; nt < 2; ++nt)
                acc2[mt][nt] = __builtin_amdgcn_mfma_f32_16x16x32_bf16(
                    a, bfr2[ks][nt], acc2[mt][nt], 0, 0, 0);
        }
    }

    #pragma unroll
    for (int nt = 0; nt < 2; ++nt) {
        const int j = w * 32 + nt * 16 + m16;
        const float b2 = ba2[j];
        #pragma unroll
        for (int mt = 0; mt < 4; ++mt)
            #pragma unroll
            for (int r = 0; r < 4; ++r) {
                const int node = n0 + mt * 16 + quad * 4 + r;
                if (node < N_NODES)
                    x_out[(size_t)node * C_OUT + j] = acc2[mt][nt][r] + b2;
            }
    }
}

// ---------- launch ----------
// ws layout (bytes):
//   segb    16,015,360   (50048 rows x 160 bf16)
//   zb      12,800,000
//   Bpack      131,072
//   Wa1b        81,920
//   Wa2b        65,536
//   cnt        200,704   (50176 ints, zero-padded for int4 scan)
//   cursor     200,704
//   offsets    200,064
//   esrc     3,200,000
//   edst     3,200,000
//   perm     3,200,000
//   eatt     3,200,000    => ~42.5 MB

extern "C" void kernel_launch(void* const* d_in, const int* in_sizes, int n_in,
                              void* d_out, int out_size, void* d_ws, size_t ws_size,
                              hipStream_t stream) {
    const float* z     = (const float*)d_in[0];
    const int*   ei    = (const int*)d_in[1];     // int32 per harness contract
    const float* eattr = (const float*)d_in[2];
    const float* Wa1   = (const float*)d_in[3];
    const float* ba1   = (const float*)d_in[4];
    const float* Wa2   = (const float*)d_in[5];
    const float* ba2   = (const float*)d_in[6];
    const float* We1   = (const float*)d_in[7];
    const float* be1   = (const float*)d_in[8];
    const float* We2   = (const float*)d_in[9];
    const float* be2   = (const float*)d_in[10];

    float* x_out    = (float*)d_out;
    float* edge_out = x_out + (size_t)N_NODES * C_OUT;

    char* wsb = (char*)d_ws;
    size_t off = 0;
    unsigned short* segb    = (unsigned short*)(wsb + off); off += 16015360;
    unsigned short* zb      = (unsigned short*)(wsb + off); off += 12800000;
    unsigned short* Bpack   = (unsigned short*)(wsb + off); off += 131072;
    unsigned short* Wa1b    = (unsigned short*)(wsb + off); off += 81920;
    unsigned short* Wa2b    = (unsigned short*)(wsb + off); off += 65536;
    int*            cnt     = (int*)(wsb + off);            off += 200704;
    int*            cursor  = (int*)(wsb + off);            off += 200704;
    int*            offsets = (int*)(wsb + off);            off += 200064;
    int*            esrc    = (int*)(wsb + off);            off += 3200000;
    int*            edst    = (int*)(wsb + off);            off += 3200000;
    int*            perm    = (int*)(wsb + off);            off += 3200000;
    float*          eatt    = (float*)(wsb + off);          off += 3200000;

    hipMemsetAsync(cnt, 0, 2 * 200704, stream);   // cnt + cursor (adjacent)

    prep_kernel<<<6250 + 3125 + 32 + 20 + 16, 256, 0, stream>>>(
        z, ei, We1, Wa1, Wa2, zb, cnt, Bpack, Wa1b, Wa2b);

    scan_kernel<<<1, 256, 0, stream>>>(cnt, offsets);
    fill_kernel<<<(N_EDGES + 255) / 256, 256, 0, stream>>>(ei, eattr, offsets, cursor,
                                                           esrc, edst, perm, eatt);

    edge_mfma_kernel<<<EDGE_GRID, 512, 0, stream>>>(zb, esrc, edst, perm, Bpack,
                                                    be1, We2, be2, edge_out);

    gather_kernel<<<(N_NODES + 3) / 4, 256, 0, stream>>>(zb, offsets, esrc, eatt, segb);
    node_mfma_kernel<<<(N_NODES + 63) / 64, 256, 0, stream>>>(segb, Wa1b, ba1, Wa2b,
                                                              ba2, x_out);
}

// Round 10
// 419.428 us; speedup vs baseline: 1.1595x; 1.1008x over previous
//
#include <hip/hip_runtime.h>

#define N_NODES 50000
#define N_EDGES 800000
#define C_IN    128
#define C_HID   256
#define C_OUT   128
#define SEGB_STRIDE 160   // bf16: [z mean 0..127 | attr 128 | zeros 129..159]
#define YSTRIDE 512       // bf16: [y_src 0..255 | y_dst 256..511]

typedef __bf16 bf16x8 __attribute__((ext_vector_type(8)));
typedef float  f32x4  __attribute__((ext_vector_type(4)));

__device__ __forceinline__ unsigned short f2bf(float x) {
    unsigned u = __float_as_uint(x);
    u = (u + 0x7FFF + ((u >> 16) & 1)) >> 16;   // RNE
    return (unsigned short)u;
}
__device__ __forceinline__ float bf2f(unsigned short h) {
    return __uint_as_float((unsigned)h << 16);
}

// ---------- fused prep: cast_z | hist | bpack | wa1b | wa2b ----------
__global__ __launch_bounds__(256) void prep_kernel(
    const float* __restrict__ z, const int* __restrict__ ei,
    const float* __restrict__ We1, const float* __restrict__ Wa1,
    const float* __restrict__ Wa2,
    unsigned short* __restrict__ zb, int* __restrict__ cnt,
    unsigned short* __restrict__ Bpack, unsigned short* __restrict__ Wa1b,
    unsigned short* __restrict__ Wa2b)
{
    const int b = blockIdx.x;
    const int tid = threadIdx.x;
    if (b < 6250) {                                   // cast_z: 6250*256 = 1.6M float4
        int t = b * 256 + tid;
        float4 v = ((const float4*)z)[t];
        ushort4 o;
        o.x = f2bf(v.x); o.y = f2bf(v.y); o.z = f2bf(v.z); o.w = f2bf(v.w);
        ((ushort4*)zb)[t] = o;
    } else if (b < 6250 + 3125) {                     // hist: 3125*256 = 800000
        int e = (b - 6250) * 256 + tid;
        atomicAdd(&cnt[ei[N_EDGES + e]], 1);
    } else if (b < 6250 + 3125 + 32) {                // Bpack (We1 B-frags, 8ks x 16nt)
        int t = (b - 6250 - 3125) * 256 + tid;        // 8192 lane-slots
        int lane = t & 63, nt = (t >> 6) & 15, ks = t >> 10;
        int n  = nt * 16 + (lane & 15);
        int kb = ks * 32 + (lane >> 4) * 8;
        #pragma unroll
        for (int j = 0; j < 8; ++j)
            Bpack[t * 8 + j] = f2bf(We1[(kb + j) * C_HID + n]);
    } else if (b < 6250 + 3125 + 32 + 20) {           // Wa1b (node layer1)
        int t = (b - 6250 - 3125 - 32) * 256 + tid;
        if (t >= 5 * 16 * 64) return;
        int lane = t & 63, nt = (t >> 6) & 15, ks = t >> 10;
        int n = nt * 16 + (lane & 15);
        #pragma unroll
        for (int j = 0; j < 8; ++j) {
            int k = ks * 32 + (lane >> 4) * 8 + j;
            float v = 0.f;
            if (k < 128)       v = Wa1[(k + 1) * C_HID + n];
            else if (k == 128) v = Wa1[0 * C_HID + n];
            Wa1b[t * 8 + j] = f2bf(v);
        }
    } else {                                          // Wa2b (node layer2)
        int t = (b - 6250 - 3125 - 32 - 20) * 256 + tid;
        if (t >= 8 * 8 * 64) return;
        int lane = t & 63, nt = (t >> 6) & 7, ks = t >> 9;
        int n  = nt * 16 + (lane & 15);
        int kb = ks * 32 + (lane >> 4) * 8;
        #pragma unroll
        for (int j = 0; j < 8; ++j)
            Wa2b[t * 8 + j] = f2bf(Wa2[(kb + j) * C_OUT + n]);
    }
}

// ---------- CSR build ----------

// cnt zero-padded to 50176 ints so int4 reads need no bounds checks.
__global__ __launch_bounds__(256) void scan_kernel(const int* __restrict__ cnt,
                                                   int* __restrict__ offsets) {
    const int tid = threadIdx.x;
    const int per = 196;                        // 49 int4
    const int base = tid * per;
    const int4* c4 = (const int4*)(cnt + base);
    int sum = 0;
    #pragma unroll 7
    for (int i = 0; i < 49; ++i) {
        int4 v = c4[i];
        sum += v.x + v.y + v.z + v.w;
    }
    const int lane = tid & 63, w = tid >> 6;
    int v = sum;
    #pragma unroll
    for (int off = 1; off < 64; off <<= 1) {
        int t = __shfl_up(v, off, 64);
        if (lane >= off) v += t;
    }
    __shared__ int s_w[4];
    if (lane == 63) s_w[w] = v;
    __syncthreads();
    int wbase = 0;
    for (int i = 0; i < w; ++i) wbase += s_w[i];
    int run = wbase + v - sum;
    for (int i = 0; i < per; ++i) {
        int b = base + i;
        if (b < N_NODES) { offsets[b] = run; run += cnt[b]; }
    }
    if (tid == 255) offsets[N_NODES] = run;
}

__global__ void fill_kernel(const int* __restrict__ ei, const float* __restrict__ eattr,
                            const int* __restrict__ offsets, int* __restrict__ cursor,
                            int* __restrict__ esrc, int* __restrict__ edst,
                            int* __restrict__ perm, float* __restrict__ eatt) {
    int e = blockIdx.x * 256 + threadIdx.x;
    if (e >= N_EDGES) return;
    int d = ei[N_EDGES + e];
    int pos = atomicAdd(&cursor[d], 1);
    int slot = offsets[d] + pos;
    esrc[slot] = ei[e];
    edst[slot] = d;
    perm[slot] = e;
    eatt[slot] = eattr[e];
}

// ---------- Y GEMM: Y[:,0:256] = zb@We1_top ; Y[:,256:512] = zb@We1_bot + be1 ----------
// M=50048 x K=128 x N=256 per half; grid (782, 2), 256 thr / 4 waves,
// wave owns 64 cols of this half. Reuses Bpack: ks 0..3 = W_top, 4..7 = W_bot.
__global__ __launch_bounds__(256, 2) void ygemm_kernel(
    const unsigned short* __restrict__ zb, const unsigned short* __restrict__ Bpack,
    const float* __restrict__ be1, unsigned short* __restrict__ Y)
{
    __shared__ __align__(16) unsigned short s_a[64][136];
    const int tid = threadIdx.x;
    const int lane = tid & 63, w = tid >> 6;
    const int m16 = lane & 15, quad = lane >> 4;
    const int n0 = blockIdx.x * 64;
    const int half = blockIdx.y;

    // stage A: 64 rows x 256B = 1024 16B-chunks, 4/thread
    #pragma unroll
    for (int i = 0; i < 4; ++i) {
        int c = tid + i * 256;
        int row = c >> 4, col = (c & 15) * 8;
        *(uint4*)&s_a[row][col] = *(const uint4*)(zb + (size_t)(n0 + row) * C_IN + col);
    }

    bf16x8 bfr[4][4];
    {
        const bf16x8* bp = (const bf16x8*)Bpack;
        #pragma unroll
        for (int ks = 0; ks < 4; ++ks)
            #pragma unroll
            for (int nt = 0; nt < 4; ++nt)
                bfr[ks][nt] = bp[((half * 4 + ks) * 16 + (w * 4 + nt)) * 64 + lane];
    }
    __syncthreads();

    f32x4 acc[4][4];
    #pragma unroll
    for (int mt = 0; mt < 4; ++mt)
        #pragma unroll
        for (int nt = 0; nt < 4; ++nt)
            acc[mt][nt] = (f32x4){0.f, 0.f, 0.f, 0.f};

    #pragma unroll
    for (int ks = 0; ks < 4; ++ks) {
        #pragma unroll
        for (int mt = 0; mt < 4; ++mt) {
            bf16x8 a = *(const bf16x8*)&s_a[mt * 16 + m16][ks * 32 + quad * 8];
            #pragma unroll
            for (int nt = 0; nt < 4; ++nt)
                acc[mt][nt] = __builtin_amdgcn_mfma_f32_16x16x32_bf16(
                    a, bfr[ks][nt], acc[mt][nt], 0, 0, 0);
        }
    }

    #pragma unroll
    for (int nt = 0; nt < 4; ++nt) {
        const int c = w * 64 + nt * 16 + m16;           // col within half
        const float b = half ? be1[c] : 0.f;
        #pragma unroll
        for (int mt = 0; mt < 4; ++mt)
            #pragma unroll
            for (int r = 0; r < 4; ++r) {
                const int node = n0 + mt * 16 + quad * 4 + r;
                Y[(size_t)node * YSTRIDE + half * 256 + c] = f2bf(acc[mt][nt][r] + b);
            }
    }
}

// ---------- edge elementwise: relu(Y[src].lo + Y[dst].hi) . We2 + be2 ----------
// No MFMA, no LDS, no barriers. Wave = 64 CSR slots; lane owns 4 channels.
// CSR order keeps Y[dst] rows cache-hot; output scattered via perm.
__global__ __launch_bounds__(256) void edge_ew_kernel(
    const unsigned short* __restrict__ Y, const int* __restrict__ esrc,
    const int* __restrict__ edst, const int* __restrict__ perm,
    const float* __restrict__ We2, const float* __restrict__ be2,
    float* __restrict__ edge_out)
{
    const int lane = threadIdx.x & 63;
    const int gw = blockIdx.x * 4 + (threadIdx.x >> 6);   // 0..12499
    float w2[4];
    #pragma unroll
    for (int j = 0; j < 4; ++j) w2[j] = We2[lane * 4 + j];
    const float be2v = be2[0];
    const int s0 = gw * 64;

    for (int i = 0; i < 64; i += 4) {
        int s[4], src[4], dst[4];
        ushort4 a[4], d[4];
        #pragma unroll
        for (int u = 0; u < 4; ++u) {
            s[u] = s0 + i + u;
            src[u] = esrc[s[u]];
            dst[u] = edst[s[u]];
        }
        #pragma unroll
        for (int u = 0; u < 4; ++u) {
            a[u] = *(const ushort4*)(Y + (size_t)src[u] * YSTRIDE + lane * 4);
            d[u] = *(const ushort4*)(Y + (size_t)dst[u] * YSTRIDE + 256 + lane * 4);
        }
        float p[4];
        #pragma unroll
        for (int u = 0; u < 4; ++u) {
            float h0 = fmaxf(bf2f(a[u].x) + bf2f(d[u].x), 0.f);
            float h1 = fmaxf(bf2f(a[u].y) + bf2f(d[u].y), 0.f);
            float h2 = fmaxf(bf2f(a[u].z) + bf2f(d[u].z), 0.f);
            float h3 = fmaxf(bf2f(a[u].w) + bf2f(d[u].w), 0.f);
            p[u] = fmaf(h0, w2[0], fmaf(h1, w2[1], fmaf(h2, w2[2], h3 * w2[3])));
        }
        #pragma unroll
        for (int off = 1; off < 64; off <<= 1)
            #pragma unroll
            for (int u = 0; u < 4; ++u)
                p[u] += __shfl_xor(p[u], off, 64);
        // after xor-tree every lane holds the full sum: lanes 0..3 store edges 0..3
        if (lane < 4) edge_out[perm[s[lane]]] = p[lane] + be2v;
    }
}

// ---------- gather-mean (bf16 in, bf16 out, fused normalize, 4x ILP) ----------
__global__ __launch_bounds__(256) void gather_kernel(
    const unsigned short* __restrict__ zb, const int* __restrict__ offsets,
    const int* __restrict__ esrc, const float* __restrict__ eatt,
    unsigned short* __restrict__ segb)
{
    const int w = threadIdx.x >> 6, lane = threadIdx.x & 63;
    const int n = blockIdx.x * 4 + w;
    if (n >= N_NODES) return;
    const int beg = offsets[n], end = offsets[n + 1], deg = end - beg;

    float ax = 0.f, ay = 0.f;                  // lane owns channels lane*2, lane*2+1
    int i = beg;
    for (; i + 4 <= end; i += 4) {
        int s0 = esrc[i], s1 = esrc[i + 1], s2 = esrc[i + 2], s3 = esrc[i + 3];
        unsigned u0 = *(const unsigned*)(zb + (size_t)s0 * C_IN + lane * 2);
        unsigned u1 = *(const unsigned*)(zb + (size_t)s1 * C_IN + lane * 2);
        unsigned u2 = *(const unsigned*)(zb + (size_t)s2 * C_IN + lane * 2);
        unsigned u3 = *(const unsigned*)(zb + (size_t)s3 * C_IN + lane * 2);
        ax += __uint_as_float(u0 << 16) + __uint_as_float(u1 << 16)
            + __uint_as_float(u2 << 16) + __uint_as_float(u3 << 16);
        ay += __uint_as_float(u0 & 0xffff0000u) + __uint_as_float(u1 & 0xffff0000u)
            + __uint_as_float(u2 & 0xffff0000u) + __uint_as_float(u3 & 0xffff0000u);
    }
    for (; i < end; ++i) {
        int s = esrc[i];
        unsigned u = *(const unsigned*)(zb + (size_t)s * C_IN + lane * 2);
        ax += __uint_as_float(u << 16);
        ay += __uint_as_float(u & 0xffff0000u);
    }
    float asum = 0.f;
    for (int j = beg + lane; j < end; j += 64) asum += eatt[j];
    #pragma unroll
    for (int off = 1; off < 64; off <<= 1) asum += __shfl_xor(asum, off, 64);

    const float inv = (deg > 0) ? 1.0f / (float)deg : 0.0f;
    unsigned short* segn = segb + (size_t)n * SEGB_STRIDE;
    ushort2 o; o.x = f2bf(ax * inv); o.y = f2bf(ay * inv);
    *(ushort2*)(segn + lane * 2) = o;
    if (lane < 16) {
        ushort2 p; p.x = (lane == 0) ? f2bf(asum * inv) : 0; p.y = 0;
        *(ushort2*)(segn + 128 + lane * 2) = p;   // attr @128, zeros 129..159
    }
}

// ---------- node MLP: bf16 MFMA, both layers, h via LDS round-trip ----------
__global__ __launch_bounds__(256, 2) void node_mfma_kernel(
    const unsigned short* __restrict__ segb, const unsigned short* __restrict__ Wa1b,
    const float* __restrict__ ba1, const unsigned short* __restrict__ Wa2b,
    const float* __restrict__ ba2, float* __restrict__ x_out)
{
    __shared__ __align__(16) unsigned short s_a[64][168];
    __shared__ __align__(16) unsigned short s_h[64][264];
    const int tid  = threadIdx.x;
    const int lane = tid & 63, w = tid >> 6;
    const int m16 = lane & 15, quad = lane >> 4;
    const int n0 = blockIdx.x * 64;

    {
        const unsigned short* src = segb + (size_t)n0 * SEGB_STRIDE;
        #pragma unroll
        for (int i = 0; i < 5; ++i) {
            int c = tid + i * 256;
            int row = c / 20, col = c - row * 20;
            *(uint4*)&s_a[row][col * 8] = *(const uint4*)(src + c * 8);
        }
    }

    bf16x8 bfr1[5][4];
    {
        const bf16x8* bp = (const bf16x8*)Wa1b;
        #pragma unroll
        for (int ks = 0; ks < 5; ++ks)
            #pragma unroll
            for (int nt = 0; nt < 4; ++nt)
                bfr1[ks][nt] = bp[(ks * 16 + (w * 4 + nt)) * 64 + lane];
    }
    __syncthreads();

    f32x4 acc1[4][4];
    #pragma unroll
    for (int mt = 0; mt < 4; ++mt)
        #pragma unroll
        for (int nt = 0; nt < 4; ++nt)
            acc1[mt][nt] = (f32x4){0.f, 0.f, 0.f, 0.f};

    #pragma unroll
    for (int ks = 0; ks < 5; ++ks) {
        #pragma unroll
        for (int mt = 0; mt < 4; ++mt) {
            bf16x8 a = *(const bf16x8*)&s_a[mt * 16 + m16][ks * 32 + quad * 8];
            #pragma unroll
            for (int nt = 0; nt < 4; ++nt)
                acc1[mt][nt] = __builtin_amdgcn_mfma_f32_16x16x32_bf16(
                    a, bfr1[ks][nt], acc1[mt][nt], 0, 0, 0);
        }
    }

    #pragma unroll
    for (int nt = 0; nt < 4; ++nt) {
        const int chan = w * 64 + nt * 16 + m16;
        const float b1 = ba1[chan];
        #pragma unroll
        for (int mt = 0; mt < 4; ++mt)
            #pragma unroll
            for (int r = 0; r < 4; ++r) {
                const int node = mt * 16 + quad * 4 + r;
                s_h[node][chan] = f2bf(fmaxf(acc1[mt][nt][r] + b1, 0.f));
            }
    }

    bf16x8 bfr2[8][2];
    {
        const bf16x8* bp = (const bf16x8*)Wa2b;
        #pragma unroll
        for (int ks = 0; ks < 8; ++ks)
            #pragma unroll
            for (int nt = 0; nt < 2; ++nt)
                bfr2[ks][nt] = bp[(ks * 8 + (w * 2 + nt)) * 64 + lane];
    }
    __syncthreads();

    f32x4 acc2[4][2];
    #pragma unroll
    for (int mt = 0; mt < 4; ++mt)
        #pragma unroll
        for (int nt = 0; nt < 2; ++nt)
            acc2[mt][nt] = (f32x4){0.f, 0.f, 0.f, 0.f};

    #pragma unroll
    for (int ks = 0; ks < 8; ++ks) {
        #pragma unroll
        for (int mt = 0; mt < 4; ++mt) {
            bf16x8 a = *(const bf16x8*)&s_h[mt * 16 + m16][ks * 32 + quad * 8];
            #pragma unroll
            for (int nt = 0; nt < 2; ++nt)
                acc2[mt][nt] = __builtin_amdgcn_mfma_f32_16x16x32_bf16(
                    a, bfr2[ks][nt], acc2[mt][nt], 0, 0, 0);
        }
    }

    #pragma unroll
    for (int nt = 0; nt < 2; ++nt) {
        const int j = w * 32 + nt * 16 + m16;
        const float b2 = ba2[j];
        #pragma unroll
        for (int mt = 0; mt < 4; ++mt)
            #pragma unroll
            for (int r = 0; r < 4; ++r) {
                const int node = n0 + mt * 16 + quad * 4 + r;
                if (node < N_NODES)
                    x_out[(size_t)node * C_OUT + j] = acc2[mt][nt][r] + b2;
            }
    }
}

// ---------- launch ----------
// ws layout (bytes), total ~77.8 MB:
//   Y       51,249,152   (50048 x 512 bf16)  [segb ALIASES Y's head: Y is dead
//                                             before gather writes segb]
//   zb      12,812,288   (50048 rows; 50000 valid, tail garbage never used)
//   Bpack      131,072
//   Wa1b        81,920
//   Wa2b        65,536
//   cnt        200,704   (50176 ints, zero-padded for int4 scan)
//   cursor     200,704
//   offsets    200,064
//   esrc     3,200,000
//   edst     3,200,000
//   perm     3,200,000
//   eatt     3,200,000

extern "C" void kernel_launch(void* const* d_in, const int* in_sizes, int n_in,
                              void* d_out, int out_size, void* d_ws, size_t ws_size,
                              hipStream_t stream) {
    const float* z     = (const float*)d_in[0];
    const int*   ei    = (const int*)d_in[1];     // int32 per harness contract
    const float* eattr = (const float*)d_in[2];
    const float* Wa1   = (const float*)d_in[3];
    const float* ba1   = (const float*)d_in[4];
    const float* Wa2   = (const float*)d_in[5];
    const float* ba2   = (const float*)d_in[6];
    const float* We1   = (const float*)d_in[7];
    const float* be1   = (const float*)d_in[8];
    const float* We2   = (const float*)d_in[9];
    const float* be2   = (const float*)d_in[10];

    float* x_out    = (float*)d_out;
    float* edge_out = x_out + (size_t)N_NODES * C_OUT;

    char* wsb = (char*)d_ws;
    size_t off = 0;
    unsigned short* Y       = (unsigned short*)(wsb + off); off += 51249152;
    unsigned short* segb    = Y;   // alias: gather writes after edge_ew drained Y
    unsigned short* zb      = (unsigned short*)(wsb + off); off += 12812288;
    unsigned short* Bpack   = (unsigned short*)(wsb + off); off += 131072;
    unsigned short* Wa1b    = (unsigned short*)(wsb + off); off += 81920;
    unsigned short* Wa2b    = (unsigned short*)(wsb + off); off += 65536;
    int*            cnt     = (int*)(wsb + off);            off += 200704;
    int*            cursor  = (int*)(wsb + off);            off += 200704;
    int*            offsets = (int*)(wsb + off);            off += 200064;
    int*            esrc    = (int*)(wsb + off);            off += 3200000;
    int*            edst    = (int*)(wsb + off);            off += 3200000;
    int*            perm    = (int*)(wsb + off);            off += 3200000;
    float*          eatt    = (float*)(wsb + off);          off += 3200000;

    hipMemsetAsync(cnt, 0, 2 * 200704, stream);   // cnt + cursor (adjacent)

    prep_kernel<<<6250 + 3125 + 32 + 20 + 16, 256, 0, stream>>>(
        z, ei, We1, Wa1, Wa2, zb, cnt, Bpack, Wa1b, Wa2b);

    scan_kernel<<<1, 256, 0, stream>>>(cnt, offsets);
    fill_kernel<<<(N_EDGES + 255) / 256, 256, 0, stream>>>(ei, eattr, offsets, cursor,
                                                           esrc, edst, perm, eatt);

    ygemm_kernel<<<dim3(782, 2), 256, 0, stream>>>(zb, Bpack, be1, Y);
    edge_ew_kernel<<<3125, 256, 0, stream>>>(Y, esrc, edst, perm, We2, be2, edge_out);

    gather_kernel<<<(N_NODES + 3) / 4, 256, 0, stream>>>(zb, offsets, esrc, eatt, segb);
    node_mfma_kernel<<<(N_NODES + 63) / 64, 256, 0, stream>>>(segb, Wa1b, ba1, Wa2b,
                                                              ba2, x_out);
}